// Round 4
// baseline (368.411 us; speedup 1.0000x reference)
//
#include <hip/hip_runtime.h>

#define NTOT 8192
#define NROW 2048
#define NU 4096
#define D 64
#define MAXN 64
#define ND (NTOT*D)

typedef float f4 __attribute__((ext_vector_type(4)));

__device__ __forceinline__ float wsum(float x){
  #pragma unroll
  for(int o=32;o;o>>=1) x += __shfl_xor(x,o);
  return x;
}
__device__ __forceinline__ float wmax(float x){
  #pragma unroll
  for(int o=32;o;o>>=1) x = fmaxf(x,__shfl_xor(x,o));
  return x;
}
__device__ __forceinline__ float bcastf(float x, int k){
  return __uint_as_float(__builtin_amdgcn_readlane(__float_as_uint(x),(unsigned)k));
}
__device__ __forceinline__ int bcasti(int x, int k){
  return (int)__builtin_amdgcn_readlane((unsigned)x,(unsigned)k);
}

// ---- k0a: concat emb + h0 = emb@gatW0+b + q0/k0 + S0 block-partials ----
__global__ __launch_bounds__(256) void k0a(const float* __restrict__ ut, const float* __restrict__ it,
    const float* __restrict__ gat_W, const float* __restrict__ gat_b, const float* __restrict__ attn_W,
    float* __restrict__ all_emb, float* __restrict__ h0,
    float* __restrict__ q0v, float* __restrict__ k0v, float* __restrict__ part0){
  __shared__ float Ws[D*D];
  __shared__ float red[4][D];
  int tid = threadIdx.x, lane = tid & 63, wid = tid >> 6;
  for(int i = tid; i < D*D; i += 256) Ws[i] = gat_W[i];
  __syncthreads();
  int row = blockIdx.x*4 + wid;
  float x = (row < NU) ? ut[row*D + lane] : it[(row-NU)*D + lane];
  all_emb[row*D + lane] = x;
  float h = gat_b[lane];
  #pragma unroll 16
  for(int k = 0; k < D; ++k) h = fmaf(bcastf(x, k), Ws[k*D + lane], h);
  h0[row*D + lane] = h;
  float q  = wsum(h * attn_W[lane]);
  float kk = wsum(h * attn_W[D + lane]);
  if(lane == 0){ q0v[row] = q; k0v[row] = kk; }
  red[wid][lane] = h;
  __syncthreads();
  if(wid == 0)
    part0[blockIdx.x*D + lane] = red[0][lane] + red[1][lane] + red[2][lane] + red[3][lane];
}

// ---- kred: deterministic reduce of NROW block-partials -> S[64] ----
__global__ __launch_bounds__(256) void kred(const float* __restrict__ part, float* __restrict__ S){
  __shared__ float red[4][D];
  int tid = threadIdx.x, lane = tid & 63, w = tid >> 6;
  float s = 0.f;
  for(int i = w; i < NROW; i += 4) s += part[i*D + lane];
  red[w][lane] = s;
  __syncthreads();
  if(tid < D) S[tid] = red[0][tid] + red[1][tid] + red[2][tid] + red[3][tid];
}

// ---- k1: adj scan (nt loads) fused with ALL layer-0 edge work ----
__global__ __launch_bounds__(256) void k1(const float* __restrict__ adj,
    const float* __restrict__ all_emb, const float* __restrict__ h0,
    const float* __restrict__ q0v, const float* __restrict__ k0v, const float* __restrict__ S0,
    const float* __restrict__ gcn_W, const float* __restrict__ gcn_b,
    const float* __restrict__ gat_W, const float* __restrict__ gat_b,
    const float* __restrict__ attn_W, const float* __restrict__ attn_b,
    const float* __restrict__ fuse_W, const float* __restrict__ fuse_b,
    const float* __restrict__ layer_w,
    int* __restrict__ ell, int* __restrict__ nnz,
    float* __restrict__ gcn1, float* __restrict__ fusedb, float* __restrict__ h1,
    float* __restrict__ q1v, float* __restrict__ k1v, float* __restrict__ part1){
  __shared__ float Ws[D*D];        // 16 KB, staged 4x
  __shared__ int colbuf[4][MAXN];  // 1 KB
  __shared__ float red[4][D];      // 1 KB
  int tid = threadIdx.x, lane = tid & 63, wid = tid >> 6;
  int row = blockIdx.x*4 + wid;

  // -- scan adj row, compact nonzero cols into colbuf --
  const f4* arow = (const f4*)(adj + (size_t)row * NTOT);
  int base = 0;
  for(int c0 = 0; c0 < NTOT/4; c0 += 64){
    f4 v = __builtin_nontemporal_load(&arow[c0 + lane]);
    int nib = (v.x!=0.f?1:0) | (v.y!=0.f?2:0) | (v.z!=0.f?4:0) | (v.w!=0.f?8:0);
    if(__ballot(nib != 0) == 0ull) continue;
    #pragma unroll
    for(int j = 0; j < 4; ++j){
      unsigned long long m = __ballot(((nib>>j)&1) != 0);
      if(m){
        if((nib>>j)&1){
          int below = __builtin_amdgcn_mbcnt_hi((unsigned)(m>>32),
                      __builtin_amdgcn_mbcnt_lo((unsigned)m, 0u));
          int slot = base + below;
          if(slot < MAXN) colbuf[wid][slot] = (c0 + lane)*4 + j;
        }
        base += __popcll(m);
      }
    }
  }
  int cnt = base > MAXN ? MAXN : base;
  int mycol = colbuf[wid][lane];            // garbage beyond cnt: always guarded
  if(lane == 0) nnz[row] = cnt;
  ell[row*MAXN + lane] = mycol;

  // -- GAT0 per-edge logits, analytic dense softmax scalars --
  float q  = q0v[row];
  float ab = attn_b[0];
  int colg = (lane < cnt) ? mycol : 0;
  float e = -1e30f;
  if(lane < cnt){
    float xx = q + k0v[colg] + ab;
    e = (xx >= 0.f) ? xx : 0.01f * xx;
  }
  float m  = fmaxf(0.f, wmax(e));
  float w  = (lane < cnt) ? expf(e - m) : 0.f;
  float em = expf(-m);
  float Z  = (float)(NTOT - cnt) * em + wsum(w);

  // -- single edge-gather loop: GCN1 nbr-sum + GAT0 weighted sum --
  float accg = 0.f, acca = 0.f, hs = 0.f;
  for(int tt = 0; tt < cnt; ++tt){
    int   c  = bcasti(mycol, tt);
    float wt = bcastf(w, tt);
    float ev = all_emb[c*D + lane];
    float hv = h0[c*D + lane];
    accg += ev;
    acca  = fmaf(wt, hv, acca);
    hs   += hv;
  }
  float g1 = fmaxf((acca + em*(S0[lane] - hs)) / Z, 0.f);   // gat1 row

  // -- gcn1 = relu(accg @ gcnW0 + b0) --
  for(int i = tid; i < D*D; i += 256) Ws[i] = gcn_W[i];
  __syncthreads();
  float yg = gcn_b[lane];
  #pragma unroll 16
  for(int k = 0; k < D; ++k) yg = fmaf(bcastf(accg, k), Ws[k*D + lane], yg);
  float gc1 = fmaxf(yg, 0.f);
  gcn1[row*D + lane] = gc1;
  __syncthreads();

  // -- fuse layer 0 --
  float l0 = layer_w[0], l1 = layer_w[1];
  float mx = fmaxf(l0, l1);
  float e0 = expf(l0 - mx), e1 = expf(l1 - mx);
  float lw0 = e0 / (e0 + e1);
  for(int i = tid; i < D*D; i += 256) Ws[i] = fuse_W[i];
  __syncthreads();
  float y = fuse_b[lane];
  #pragma unroll 16
  for(int k = 0; k < D; ++k) y = fmaf(bcastf(gc1, k), Ws[k*D + lane], y);
  __syncthreads();
  for(int i = tid; i < D*D; i += 256) Ws[i] = fuse_W[D*D + i];
  __syncthreads();
  #pragma unroll 16
  for(int k = 0; k < D; ++k) y = fmaf(bcastf(g1, k), Ws[k*D + lane], y);
  fusedb[row*D + lane] = lw0 * fmaxf(y, 0.f);
  __syncthreads();

  // -- h1 = gat1 @ gatW1 + b1, q1/k1, S1 partials --
  for(int i = tid; i < D*D; i += 256) Ws[i] = gat_W[D*D + i];
  __syncthreads();
  float h = gat_b[D + lane];
  #pragma unroll 16
  for(int k = 0; k < D; ++k) h = fmaf(bcastf(g1, k), Ws[k*D + lane], h);
  h1[row*D + lane] = h;
  float qq = wsum(h * attn_W[2*D + lane]);
  float kk = wsum(h * attn_W[3*D + lane]);
  if(lane == 0){ q1v[row] = qq; k1v[row] = kk; }
  red[wid][lane] = h;
  __syncthreads();
  if(wid == 0)
    part1[blockIdx.x*D + lane] = red[0][lane] + red[1][lane] + red[2][lane] + red[3][lane];
}

// ---- k2: GCN2 gather + GAT1 attn + fuse1, all from ELL ----
__global__ __launch_bounds__(256) void k2(
    const int* __restrict__ ell, const int* __restrict__ nnz,
    const float* __restrict__ gcn1, const float* __restrict__ h1,
    const float* __restrict__ q1v, const float* __restrict__ k1v, const float* __restrict__ S1,
    const float* __restrict__ gcn_W, const float* __restrict__ gcn_b,
    const float* __restrict__ attn_b,
    const float* __restrict__ fuse_W, const float* __restrict__ fuse_b,
    const float* __restrict__ layer_w,
    float* __restrict__ fusedb){
  __shared__ float Ws[D*D];
  int tid = threadIdx.x, lane = tid & 63, wid = tid >> 6;
  int row = blockIdx.x*4 + wid;
  int cnt = nnz[row];
  int mycol = ell[row*MAXN + lane];
  float q  = q1v[row];
  float ab = attn_b[1];
  int colg = (lane < cnt) ? mycol : 0;
  float e = -1e30f;
  if(lane < cnt){
    float xx = q + k1v[colg] + ab;
    e = (xx >= 0.f) ? xx : 0.01f * xx;
  }
  float m  = fmaxf(0.f, wmax(e));
  float w  = (lane < cnt) ? expf(e - m) : 0.f;
  float em = expf(-m);
  float Z  = (float)(NTOT - cnt) * em + wsum(w);
  float accg = 0.f, acca = 0.f, hs = 0.f;
  for(int tt = 0; tt < cnt; ++tt){
    int   c  = bcasti(mycol, tt);
    float wt = bcastf(w, tt);
    float gv = gcn1[c*D + lane];
    float hv = h1[c*D + lane];
    accg += gv;
    acca  = fmaf(wt, hv, acca);
    hs   += hv;
  }
  float g2 = fmaxf((acca + em*(S1[lane] - hs)) / Z, 0.f);

  for(int i = tid; i < D*D; i += 256) Ws[i] = gcn_W[D*D + i];
  __syncthreads();
  float yg = gcn_b[D + lane];
  #pragma unroll 16
  for(int k = 0; k < D; ++k) yg = fmaf(bcastf(accg, k), Ws[k*D + lane], yg);
  float gc2 = fmaxf(yg, 0.f);
  __syncthreads();

  float l0 = layer_w[0], l1 = layer_w[1];
  float mx = fmaxf(l0, l1);
  float e0 = expf(l0 - mx), e1 = expf(l1 - mx);
  float lw1 = e1 / (e0 + e1);
  for(int i = tid; i < D*D; i += 256) Ws[i] = fuse_W[2*D*D + i];
  __syncthreads();
  float y = fuse_b[D + lane];
  #pragma unroll 16
  for(int k = 0; k < D; ++k) y = fmaf(bcastf(gc2, k), Ws[k*D + lane], y);
  __syncthreads();
  for(int i = tid; i < D*D; i += 256) Ws[i] = fuse_W[3*D*D + i];
  __syncthreads();
  #pragma unroll 16
  for(int k = 0; k < D; ++k) y = fmaf(bcastf(g2, k), Ws[k*D + lane], y);
  fusedb[row*D + lane] += lw1 * fmaxf(y, 0.f);
}

// ---- k3: scoring + critic ----
__global__ __launch_bounds__(256) void k3(const float* __restrict__ fused,
    const int* __restrict__ users, const int* __restrict__ pos, const int* __restrict__ neg,
    const float* __restrict__ AW, const float* __restrict__ abias,
    const float* __restrict__ cW1, const float* __restrict__ cb1,
    const float* __restrict__ cW2, const float* __restrict__ cb2,
    float* __restrict__ out){
  __shared__ float AWs[D*D];
  __shared__ float C1s[2*D*D];
  __shared__ float abs_[D], cb1s[D], C2s[D];
  int tid = threadIdx.x;
  for(int i = tid; i < D*D; i += 256) AWs[i] = AW[i];
  for(int i = tid; i < 2*D*D; i += 256) C1s[i] = cW1[i];
  if(tid < D){
    abs_[tid] = abias[tid];
    cb1s[tid] = cb1[tid];
    C2s[tid]  = cW2[tid];
  }
  __syncthreads();
  int lane = tid & 63;
  int bi   = blockIdx.x*4 + (tid >> 6);
  int ui = users[bi], pi = pos[bi] + NU, ni = neg[bi] + NU;
  float ud = fused[ui*D + lane], pd = fused[pi*D + lane], nd = fused[ni*D + lane];
  float ufd = abs_[lane];
  #pragma unroll 16
  for(int k = 0; k < D; ++k) ufd = fmaf(bcastf(ud, k), AWs[k*D + lane], ufd);
  float ps = wsum(ufd * pd);
  float ns = wsum(ufd * nd);
  float hu = cb1s[lane];
  #pragma unroll 16
  for(int k = 0; k < D; ++k) hu = fmaf(bcastf(ud, k), C1s[k*D + lane], hu);
  float hp = hu, hn = hu;
  #pragma unroll 16
  for(int k = 0; k < D; ++k){
    float pk = bcastf(pd, k), nk = bcastf(nd, k);
    hp = fmaf(pk, C1s[(D+k)*D + lane], hp);
    hn = fmaf(nk, C1s[(D+k)*D + lane], hn);
  }
  hp = fmaxf(hp, 0.f); hn = fmaxf(hn, 0.f);
  float cp = wsum(hp * C2s[lane]);
  float cn = wsum(hn * C2s[lane]);
  if(lane == 0){
    out[bi]         = ps;
    out[4096  + bi] = ns;
    out[8192  + bi] = cp + cb2[0];
    out[12288 + bi] = cn + cb2[0];
  }
}

extern "C" void kernel_launch(void* const* d_in, const int* in_sizes, int n_in,
                              void* d_out, int out_size, void* d_ws, size_t ws_size,
                              hipStream_t stream){
  const float* adj        = (const float*)d_in[0];
  const int*   users      = (const int*)d_in[1];
  const int*   pos        = (const int*)d_in[2];
  const int*   neg        = (const int*)d_in[3];
  const float* user_table = (const float*)d_in[4];
  const float* item_table = (const float*)d_in[5];
  const float* gcn_W      = (const float*)d_in[6];
  const float* gcn_b      = (const float*)d_in[7];
  const float* gat_W      = (const float*)d_in[8];
  const float* gat_b      = (const float*)d_in[9];
  const float* attn_W     = (const float*)d_in[10];
  const float* attn_b     = (const float*)d_in[11];
  const float* fuse_W     = (const float*)d_in[12];
  const float* fuse_b     = (const float*)d_in[13];
  const float* actor_W    = (const float*)d_in[14];
  const float* actor_b    = (const float*)d_in[15];
  const float* cW1        = (const float*)d_in[16];
  const float* cb1        = (const float*)d_in[17];
  const float* cW2        = (const float*)d_in[18];
  const float* cb2        = (const float*)d_in[19];
  const float* layer_w    = (const float*)d_in[20];

  float* ws      = (float*)d_ws;
  float* all_emb = ws;                   // ND
  float* h0      = all_emb + ND;         // ND
  float* h1      = h0 + ND;              // ND
  float* gcn1    = h1 + ND;              // ND
  float* fusedb  = gcn1 + ND;            // ND
  float* q0v     = fusedb + ND;          // NTOT
  float* k0v     = q0v + NTOT;
  float* q1v     = k0v + NTOT;
  float* k1v     = q1v + NTOT;
  float* S0      = k1v + NTOT;           // D
  float* S1      = S0 + D;               // D
  float* part0   = S1 + D;               // NROW*D
  float* part1   = part0 + NROW*D;       // NROW*D
  int*   nnz     = (int*)(part1 + NROW*D);  // NTOT
  int*   ell     = nnz + NTOT;           // NTOT*MAXN

  k0a<<<NROW, 256, 0, stream>>>(user_table, item_table, gat_W, gat_b, attn_W,
                                all_emb, h0, q0v, k0v, part0);
  kred<<<1, 256, 0, stream>>>(part0, S0);
  k1<<<NROW, 256, 0, stream>>>(adj, all_emb, h0, q0v, k0v, S0,
                               gcn_W, gcn_b, gat_W, gat_b, attn_W, attn_b,
                               fuse_W, fuse_b, layer_w,
                               ell, nnz, gcn1, fusedb, h1, q1v, k1v, part1);
  kred<<<1, 256, 0, stream>>>(part1, S1);
  k2<<<NROW, 256, 0, stream>>>(ell, nnz, gcn1, h1, q1v, k1v, S1,
                               gcn_W, gcn_b, attn_b, fuse_W, fuse_b, layer_w,
                               fusedb);
  k3<<<1024, 256, 0, stream>>>(fusedb, users, pos, neg, actor_W, actor_b,
                               cW1, cb1, cW2, cb2, (float*)d_out);
}

// Round 5
// 366.063 us; speedup vs baseline: 1.0064x; 1.0064x over previous
//
#include <hip/hip_runtime.h>

#define NTOT 8192
#define NROW 2048
#define NU 4096
#define D 64
#define MAXN 64
#define ND (NTOT*D)

typedef float f4 __attribute__((ext_vector_type(4)));

__device__ __forceinline__ float wsum(float x){
  #pragma unroll
  for(int o=32;o;o>>=1) x += __shfl_xor(x,o);
  return x;
}
__device__ __forceinline__ float wmax(float x){
  #pragma unroll
  for(int o=32;o;o>>=1) x = fmaxf(x,__shfl_xor(x,o));
  return x;
}
__device__ __forceinline__ float bcastf(float x, int k){
  return __uint_as_float(__builtin_amdgcn_readlane(__float_as_uint(x),(unsigned)k));
}
__device__ __forceinline__ int bcasti(int x, int k){
  return (int)__builtin_amdgcn_readlane((unsigned)x,(unsigned)k);
}

// ---- build_ell: adj scan with depth-1 prefetch (regular loads, no NT) ----
__global__ __launch_bounds__(256) void build_ell(const float* __restrict__ adj,
                                                 int* __restrict__ ell, int* __restrict__ nnz){
  int tid = threadIdx.x, lane = tid & 63, wid = tid >> 6;
  int row = blockIdx.x*4 + wid;
  const f4* arow = (const f4*)(adj + (size_t)row * NTOT);
  int base = 0;
  f4 v = arow[lane];
  for(int c0 = 0; c0 < NTOT/4; c0 += 64){
    f4 vn = {0.f,0.f,0.f,0.f};
    if(c0 + 64 < NTOT/4) vn = arow[c0 + 64 + lane];
    int nib = (v.x!=0.f?1:0) | (v.y!=0.f?2:0) | (v.z!=0.f?4:0) | (v.w!=0.f?8:0);
    if(__ballot(nib != 0) != 0ull){
      #pragma unroll
      for(int j = 0; j < 4; ++j){
        unsigned long long m = __ballot(((nib>>j)&1) != 0);
        if(m){
          if((nib>>j)&1){
            int below = __builtin_amdgcn_mbcnt_hi((unsigned)(m>>32),
                        __builtin_amdgcn_mbcnt_lo((unsigned)m, 0u));
            int slot = base + below;
            if(slot < MAXN) ell[row*MAXN + slot] = (c0 + lane)*4 + j;
          }
          base += __popcll(m);
        }
      }
    }
    v = vn;
  }
  if(lane == 0) nnz[row] = base > MAXN ? MAXN : base;
}

// ---- k0a: concat emb + h0 = emb@gatW0+b + q0/k0 + S0 block-partials ----
__global__ __launch_bounds__(256) void k0a(const float* __restrict__ ut, const float* __restrict__ it,
    const float* __restrict__ gat_W, const float* __restrict__ gat_b, const float* __restrict__ attn_W,
    float* __restrict__ all_emb, float* __restrict__ h0,
    float* __restrict__ q0v, float* __restrict__ k0v, float* __restrict__ part0){
  __shared__ float Ws[D*D];
  __shared__ float red[4][D];
  int tid = threadIdx.x, lane = tid & 63, wid = tid >> 6;
  for(int i = tid; i < D*D; i += 256) Ws[i] = gat_W[i];
  int row = blockIdx.x*4 + wid;
  float x = (row < NU) ? ut[row*D + lane] : it[(row-NU)*D + lane];
  all_emb[row*D + lane] = x;
  __syncthreads();
  float h = gat_b[lane];
  #pragma unroll 16
  for(int k = 0; k < D; ++k) h = fmaf(bcastf(x, k), Ws[k*D + lane], h);
  h0[row*D + lane] = h;
  float q  = wsum(h * attn_W[lane]);
  float kk = wsum(h * attn_W[D + lane]);
  if(lane == 0){ q0v[row] = q; k0v[row] = kk; }
  red[wid][lane] = h;
  __syncthreads();
  if(wid == 0)
    part0[blockIdx.x*D + lane] = red[0][lane] + red[1][lane] + red[2][lane] + red[3][lane];
}

// ---- kred: deterministic reduce of NROW block-partials -> S[64] ----
__global__ __launch_bounds__(256) void kred(const float* __restrict__ part, float* __restrict__ S){
  __shared__ float red[4][D];
  int tid = threadIdx.x, lane = tid & 63, w = tid >> 6;
  float s = 0.f;
  for(int i = w; i < NROW; i += 4) s += part[i*D + lane];
  red[w][lane] = s;
  __syncthreads();
  if(tid < D) S[tid] = red[0][tid] + red[1][tid] + red[2][tid] + red[3][tid];
}

// ---- k1: layer-0 edge work from ELL (4-way unrolled gathers) ----
__global__ __launch_bounds__(256) void k1(
    const float* __restrict__ all_emb, const float* __restrict__ h0,
    const float* __restrict__ q0v, const float* __restrict__ k0v, const float* __restrict__ S0,
    const int* __restrict__ ell, const int* __restrict__ nnz,
    const float* __restrict__ gcn_W, const float* __restrict__ gcn_b,
    const float* __restrict__ gat_W, const float* __restrict__ gat_b,
    const float* __restrict__ attn_W, const float* __restrict__ attn_b,
    const float* __restrict__ fuse_W, const float* __restrict__ fuse_b,
    const float* __restrict__ layer_w,
    float* __restrict__ gcn1, float* __restrict__ fusedb, float* __restrict__ h1,
    float* __restrict__ q1v, float* __restrict__ k1v, float* __restrict__ part1){
  __shared__ float Ws[D*D];
  __shared__ float red[4][D];
  int tid = threadIdx.x, lane = tid & 63, wid = tid >> 6;
  int row = blockIdx.x*4 + wid;
  int cnt = nnz[row];
  int mycol = ell[row*MAXN + lane];

  // stage gcn_W early; barrier deferred past the gather
  for(int i = tid; i < D*D; i += 256) Ws[i] = gcn_W[i];

  // GAT0 logits + analytic softmax scalars
  float q  = q0v[row];
  float ab = attn_b[0];
  int colg = (lane < cnt) ? mycol : 0;
  float e = -1e30f;
  if(lane < cnt){
    float xx = q + k0v[colg] + ab;
    e = (xx >= 0.f) ? xx : 0.01f * xx;
  }
  float m  = fmaxf(0.f, wmax(e));
  float w  = (lane < cnt) ? expf(e - m) : 0.f;
  float em = expf(-m);
  float Z  = (float)(NTOT - cnt) * em + wsum(w);

  // 4-way unrolled gather: GCN1 nbr-sum + GAT0 weighted sum
  float accg = 0.f, acca = 0.f, hs = 0.f;
  int tt = 0;
  for(; tt + 4 <= cnt; tt += 4){
    int c0 = bcasti(mycol, tt),   c1 = bcasti(mycol, tt+1);
    int c2 = bcasti(mycol, tt+2), c3 = bcasti(mycol, tt+3);
    float w0 = bcastf(w, tt),   w1 = bcastf(w, tt+1);
    float w2 = bcastf(w, tt+2), w3 = bcastf(w, tt+3);
    float e0 = all_emb[c0*D + lane], e1 = all_emb[c1*D + lane];
    float e2 = all_emb[c2*D + lane], e3 = all_emb[c3*D + lane];
    float h0v = h0[c0*D + lane], h1v = h0[c1*D + lane];
    float h2v = h0[c2*D + lane], h3v = h0[c3*D + lane];
    accg += (e0 + e1) + (e2 + e3);
    acca = fmaf(w0, h0v, fmaf(w1, h1v, fmaf(w2, h2v, fmaf(w3, h3v, acca))));
    hs   += (h0v + h1v) + (h2v + h3v);
  }
  for(; tt < cnt; ++tt){
    int   c  = bcasti(mycol, tt);
    float wt = bcastf(w, tt);
    float ev = all_emb[c*D + lane];
    float hv = h0[c*D + lane];
    accg += ev;
    acca  = fmaf(wt, hv, acca);
    hs   += hv;
  }
  float g1 = fmaxf((acca + em*(S0[lane] - hs)) / Z, 0.f);

  // gcn1 = relu(accg @ gcnW0 + b0)
  __syncthreads();
  float yg = gcn_b[lane];
  #pragma unroll 16
  for(int k = 0; k < D; ++k) yg = fmaf(bcastf(accg, k), Ws[k*D + lane], yg);
  float gc1 = fmaxf(yg, 0.f);
  gcn1[row*D + lane] = gc1;
  __syncthreads();

  // fuse layer 0
  float l0 = layer_w[0], l1 = layer_w[1];
  float mx = fmaxf(l0, l1);
  float ex0 = expf(l0 - mx), ex1 = expf(l1 - mx);
  float lw0 = ex0 / (ex0 + ex1);
  for(int i = tid; i < D*D; i += 256) Ws[i] = fuse_W[i];
  __syncthreads();
  float y = fuse_b[lane];
  #pragma unroll 16
  for(int k = 0; k < D; ++k) y = fmaf(bcastf(gc1, k), Ws[k*D + lane], y);
  __syncthreads();
  for(int i = tid; i < D*D; i += 256) Ws[i] = fuse_W[D*D + i];
  __syncthreads();
  #pragma unroll 16
  for(int k = 0; k < D; ++k) y = fmaf(bcastf(g1, k), Ws[k*D + lane], y);
  fusedb[row*D + lane] = lw0 * fmaxf(y, 0.f);
  __syncthreads();

  // h1 = gat1 @ gatW1 + b1, q1/k1, S1 partials
  for(int i = tid; i < D*D; i += 256) Ws[i] = gat_W[D*D + i];
  __syncthreads();
  float h = gat_b[D + lane];
  #pragma unroll 16
  for(int k = 0; k < D; ++k) h = fmaf(bcastf(g1, k), Ws[k*D + lane], h);
  h1[row*D + lane] = h;
  float qq = wsum(h * attn_W[2*D + lane]);
  float kk = wsum(h * attn_W[3*D + lane]);
  if(lane == 0){ q1v[row] = qq; k1v[row] = kk; }
  red[wid][lane] = h;
  __syncthreads();
  if(wid == 0)
    part1[blockIdx.x*D + lane] = red[0][lane] + red[1][lane] + red[2][lane] + red[3][lane];
}

// ---- k2: GCN2 gather + GAT1 attn + fuse1 (4-way unrolled gathers) ----
__global__ __launch_bounds__(256) void k2(
    const int* __restrict__ ell, const int* __restrict__ nnz,
    const float* __restrict__ gcn1, const float* __restrict__ h1,
    const float* __restrict__ q1v, const float* __restrict__ k1v, const float* __restrict__ S1,
    const float* __restrict__ gcn_W, const float* __restrict__ gcn_b,
    const float* __restrict__ attn_b,
    const float* __restrict__ fuse_W, const float* __restrict__ fuse_b,
    const float* __restrict__ layer_w,
    float* __restrict__ fusedb){
  __shared__ float Ws[D*D];
  int tid = threadIdx.x, lane = tid & 63, wid = tid >> 6;
  int row = blockIdx.x*4 + wid;
  int cnt = nnz[row];
  int mycol = ell[row*MAXN + lane];

  for(int i = tid; i < D*D; i += 256) Ws[i] = gcn_W[D*D + i];

  float q  = q1v[row];
  float ab = attn_b[1];
  int colg = (lane < cnt) ? mycol : 0;
  float e = -1e30f;
  if(lane < cnt){
    float xx = q + k1v[colg] + ab;
    e = (xx >= 0.f) ? xx : 0.01f * xx;
  }
  float m  = fmaxf(0.f, wmax(e));
  float w  = (lane < cnt) ? expf(e - m) : 0.f;
  float em = expf(-m);
  float Z  = (float)(NTOT - cnt) * em + wsum(w);

  float accg = 0.f, acca = 0.f, hs = 0.f;
  int tt = 0;
  for(; tt + 4 <= cnt; tt += 4){
    int c0 = bcasti(mycol, tt),   c1 = bcasti(mycol, tt+1);
    int c2 = bcasti(mycol, tt+2), c3 = bcasti(mycol, tt+3);
    float w0 = bcastf(w, tt),   w1 = bcastf(w, tt+1);
    float w2 = bcastf(w, tt+2), w3 = bcastf(w, tt+3);
    float g0 = gcn1[c0*D + lane], g1_ = gcn1[c1*D + lane];
    float g2_ = gcn1[c2*D + lane], g3 = gcn1[c3*D + lane];
    float h0v = h1[c0*D + lane], h1v = h1[c1*D + lane];
    float h2v = h1[c2*D + lane], h3v = h1[c3*D + lane];
    accg += (g0 + g1_) + (g2_ + g3);
    acca = fmaf(w0, h0v, fmaf(w1, h1v, fmaf(w2, h2v, fmaf(w3, h3v, acca))));
    hs   += (h0v + h1v) + (h2v + h3v);
  }
  for(; tt < cnt; ++tt){
    int   c  = bcasti(mycol, tt);
    float wt = bcastf(w, tt);
    float gv = gcn1[c*D + lane];
    float hv = h1[c*D + lane];
    accg += gv;
    acca  = fmaf(wt, hv, acca);
    hs   += hv;
  }
  float g2 = fmaxf((acca + em*(S1[lane] - hs)) / Z, 0.f);

  __syncthreads();
  float yg = gcn_b[D + lane];
  #pragma unroll 16
  for(int k = 0; k < D; ++k) yg = fmaf(bcastf(accg, k), Ws[k*D + lane], yg);
  float gc2 = fmaxf(yg, 0.f);
  __syncthreads();

  float l0 = layer_w[0], l1 = layer_w[1];
  float mx = fmaxf(l0, l1);
  float ex0 = expf(l0 - mx), ex1 = expf(l1 - mx);
  float lw1 = ex1 / (ex0 + ex1);
  for(int i = tid; i < D*D; i += 256) Ws[i] = fuse_W[2*D*D + i];
  __syncthreads();
  float y = fuse_b[D + lane];
  #pragma unroll 16
  for(int k = 0; k < D; ++k) y = fmaf(bcastf(gc2, k), Ws[k*D + lane], y);
  __syncthreads();
  for(int i = tid; i < D*D; i += 256) Ws[i] = fuse_W[3*D*D + i];
  __syncthreads();
  #pragma unroll 16
  for(int k = 0; k < D; ++k) y = fmaf(bcastf(g2, k), Ws[k*D + lane], y);
  fusedb[row*D + lane] += lw1 * fmaxf(y, 0.f);
}

// ---- k3: scoring + critic ----
__global__ __launch_bounds__(256) void k3(const float* __restrict__ fused,
    const int* __restrict__ users, const int* __restrict__ pos, const int* __restrict__ neg,
    const float* __restrict__ AW, const float* __restrict__ abias,
    const float* __restrict__ cW1, const float* __restrict__ cb1,
    const float* __restrict__ cW2, const float* __restrict__ cb2,
    float* __restrict__ out){
  __shared__ float AWs[D*D];
  __shared__ float C1s[2*D*D];
  __shared__ float abs_[D], cb1s[D], C2s[D];
  int tid = threadIdx.x;
  for(int i = tid; i < D*D; i += 256) AWs[i] = AW[i];
  for(int i = tid; i < 2*D*D; i += 256) C1s[i] = cW1[i];
  if(tid < D){
    abs_[tid] = abias[tid];
    cb1s[tid] = cb1[tid];
    C2s[tid]  = cW2[tid];
  }
  __syncthreads();
  int lane = tid & 63;
  int bi   = blockIdx.x*4 + (tid >> 6);
  int ui = users[bi], pi = pos[bi] + NU, ni = neg[bi] + NU;
  float ud = fused[ui*D + lane], pd = fused[pi*D + lane], nd = fused[ni*D + lane];
  float ufd = abs_[lane];
  #pragma unroll 16
  for(int k = 0; k < D; ++k) ufd = fmaf(bcastf(ud, k), AWs[k*D + lane], ufd);
  float ps = wsum(ufd * pd);
  float ns = wsum(ufd * nd);
  float hu = cb1s[lane];
  #pragma unroll 16
  for(int k = 0; k < D; ++k) hu = fmaf(bcastf(ud, k), C1s[k*D + lane], hu);
  float hp = hu, hn = hu;
  #pragma unroll 16
  for(int k = 0; k < D; ++k){
    float pk = bcastf(pd, k), nk = bcastf(nd, k);
    hp = fmaf(pk, C1s[(D+k)*D + lane], hp);
    hn = fmaf(nk, C1s[(D+k)*D + lane], hn);
  }
  hp = fmaxf(hp, 0.f); hn = fmaxf(hn, 0.f);
  float cp = wsum(hp * C2s[lane]);
  float cn = wsum(hn * C2s[lane]);
  if(lane == 0){
    out[bi]         = ps;
    out[4096  + bi] = ns;
    out[8192  + bi] = cp + cb2[0];
    out[12288 + bi] = cn + cb2[0];
  }
}

extern "C" void kernel_launch(void* const* d_in, const int* in_sizes, int n_in,
                              void* d_out, int out_size, void* d_ws, size_t ws_size,
                              hipStream_t stream){
  const float* adj        = (const float*)d_in[0];
  const int*   users      = (const int*)d_in[1];
  const int*   pos        = (const int*)d_in[2];
  const int*   neg        = (const int*)d_in[3];
  const float* user_table = (const float*)d_in[4];
  const float* item_table = (const float*)d_in[5];
  const float* gcn_W      = (const float*)d_in[6];
  const float* gcn_b      = (const float*)d_in[7];
  const float* gat_W      = (const float*)d_in[8];
  const float* gat_b      = (const float*)d_in[9];
  const float* attn_W     = (const float*)d_in[10];
  const float* attn_b     = (const float*)d_in[11];
  const float* fuse_W     = (const float*)d_in[12];
  const float* fuse_b     = (const float*)d_in[13];
  const float* actor_W    = (const float*)d_in[14];
  const float* actor_b    = (const float*)d_in[15];
  const float* cW1        = (const float*)d_in[16];
  const float* cb1        = (const float*)d_in[17];
  const float* cW2        = (const float*)d_in[18];
  const float* cb2        = (const float*)d_in[19];
  const float* layer_w    = (const float*)d_in[20];

  float* ws      = (float*)d_ws;
  float* all_emb = ws;                   // ND
  float* h0      = all_emb + ND;         // ND
  float* h1      = h0 + ND;              // ND
  float* gcn1    = h1 + ND;              // ND
  float* fusedb  = gcn1 + ND;            // ND
  float* q0v     = fusedb + ND;          // NTOT
  float* k0v     = q0v + NTOT;
  float* q1v     = k0v + NTOT;
  float* k1v     = q1v + NTOT;
  float* S0      = k1v + NTOT;           // D
  float* S1      = S0 + D;               // D
  float* part0   = S1 + D;               // NROW*D
  float* part1   = part0 + NROW*D;       // NROW*D
  int*   nnz     = (int*)(part1 + NROW*D);  // NTOT
  int*   ell     = nnz + NTOT;           // NTOT*MAXN

  build_ell<<<NROW, 256, 0, stream>>>(adj, ell, nnz);
  k0a<<<NROW, 256, 0, stream>>>(user_table, item_table, gat_W, gat_b, attn_W,
                                all_emb, h0, q0v, k0v, part0);
  kred<<<1, 256, 0, stream>>>(part0, S0);
  k1<<<NROW, 256, 0, stream>>>(all_emb, h0, q0v, k0v, S0, ell, nnz,
                               gcn_W, gcn_b, gat_W, gat_b, attn_W, attn_b,
                               fuse_W, fuse_b, layer_w,
                               gcn1, fusedb, h1, q1v, k1v, part1);
  kred<<<1, 256, 0, stream>>>(part1, S1);
  k2<<<NROW, 256, 0, stream>>>(ell, nnz, gcn1, h1, q1v, k1v, S1,
                               gcn_W, gcn_b, attn_b, fuse_W, fuse_b, layer_w,
                               fusedb);
  k3<<<1024, 256, 0, stream>>>(fusedb, users, pos, neg, actor_W, actor_b,
                               cW1, cb1, cW2, cb2, (float*)d_out);
}

// Round 6
// 206.538 us; speedup vs baseline: 1.7837x; 1.7724x over previous
//
#include <hip/hip_runtime.h>

#define NTOT 8192
#define NU 4096
#define D 64
#define MAXN 64
#define ND (NTOT*D)

typedef float f4 __attribute__((ext_vector_type(4)));

__device__ __forceinline__ float wsum(float x){
  #pragma unroll
  for(int o=32;o;o>>=1) x += __shfl_xor(x,o);
  return x;
}
__device__ __forceinline__ float wmax(float x){
  #pragma unroll
  for(int o=32;o;o>>=1) x = fmaxf(x,__shfl_xor(x,o));
  return x;
}
__device__ __forceinline__ float bcastf(float x, int k){
  return __uint_as_float(__builtin_amdgcn_readlane(__float_as_uint(x),(unsigned)k));
}
__device__ __forceinline__ int bcasti(int x, int k){
  return (int)__builtin_amdgcn_readlane((unsigned)x,(unsigned)k);
}

// ---- init: zero the atomic accumulators (must run every call) ----
__global__ void kinit(float* __restrict__ S0, float* __restrict__ S1){
  if(threadIdx.x < D){ S0[threadIdx.x] = 0.f; S1[threadIdx.x] = 0.f; }
}

// ---- kA: adj scan -> ELL, + concat emb + h0 matmul + q0/k0 + S0 atomic ----
__global__ __launch_bounds__(256) void kA(const float* __restrict__ adj,
    const float* __restrict__ ut, const float* __restrict__ it,
    const float* __restrict__ gat_W, const float* __restrict__ gat_b,
    const float* __restrict__ attn_W,
    float* __restrict__ all_emb, float* __restrict__ h0,
    float* __restrict__ q0v, float* __restrict__ k0v, float* __restrict__ S0,
    int* __restrict__ ell, int* __restrict__ nnz){
  __shared__ float Ws[D*D];
  __shared__ float red[4][D];
  int tid = threadIdx.x, lane = tid & 63, wid = tid >> 6;
  int row = blockIdx.x*4 + wid;
  for(int i = tid; i < D*D; i += 256) Ws[i] = gat_W[i];

  // concat (own row) — keep x in register for the matmul below
  float x = (row < NU) ? ut[row*D + lane] : it[(row-NU)*D + lane];
  all_emb[row*D + lane] = x;

  // scan adjacency row (R1/R2-validated pattern)
  const f4* arow = (const f4*)(adj + (size_t)row * NTOT);
  int base = 0;
  for(int c0 = 0; c0 < NTOT/4; c0 += 64){
    f4 v = arow[c0 + lane];
    int nib = (v.x!=0.f?1:0) | (v.y!=0.f?2:0) | (v.z!=0.f?4:0) | (v.w!=0.f?8:0);
    if(__ballot(nib != 0) == 0ull) continue;
    #pragma unroll
    for(int j = 0; j < 4; ++j){
      unsigned long long m = __ballot(((nib>>j)&1) != 0);
      if(m){
        if((nib>>j)&1){
          int below = __builtin_amdgcn_mbcnt_hi((unsigned)(m>>32),
                      __builtin_amdgcn_mbcnt_lo((unsigned)m, 0u));
          int slot = base + below;
          if(slot < MAXN) ell[row*MAXN + slot] = (c0 + lane)*4 + j;
        }
        base += __popcll(m);
      }
    }
  }
  int cnt = base > MAXN ? MAXN : base;
  if(lane == 0) nnz[row] = cnt;

  // h0 = x @ gatW0 + b0 (weights staged above)
  __syncthreads();
  float h = gat_b[lane];
  #pragma unroll 16
  for(int k = 0; k < D; ++k) h = fmaf(bcastf(x, k), Ws[k*D + lane], h);
  h0[row*D + lane] = h;
  float q  = wsum(h * attn_W[lane]);
  float kk = wsum(h * attn_W[D + lane]);
  if(lane == 0){ q0v[row] = q; k0v[row] = kk; }
  red[wid][lane] = h;
  __syncthreads();
  if(wid == 0)
    atomicAdd(&S0[lane], red[0][lane] + red[1][lane] + red[2][lane] + red[3][lane]);
}

// ---- kB: gcn1 + GAT0 analytic attn + fuse0 + h1/q1/k1 + S1 atomic ----
__global__ __launch_bounds__(256) void kB(
    const float* __restrict__ all_emb, const float* __restrict__ h0,
    const float* __restrict__ q0v, const float* __restrict__ k0v, const float* __restrict__ S0,
    const int* __restrict__ ell, const int* __restrict__ nnz,
    const float* __restrict__ gcn_W, const float* __restrict__ gcn_b,
    const float* __restrict__ gat_W, const float* __restrict__ gat_b,
    const float* __restrict__ attn_W, const float* __restrict__ attn_b,
    const float* __restrict__ fuse_W, const float* __restrict__ fuse_b,
    const float* __restrict__ layer_w,
    float* __restrict__ gcn1, float* __restrict__ fusedb, float* __restrict__ h1,
    float* __restrict__ q1v, float* __restrict__ k1v, float* __restrict__ S1){
  __shared__ float Ws[D*D];
  __shared__ float red[4][D];
  int tid = threadIdx.x, lane = tid & 63, wid = tid >> 6;
  int row = blockIdx.x*4 + wid;
  int cnt = nnz[row];
  int mycol = ell[row*MAXN + lane];

  for(int i = tid; i < D*D; i += 256) Ws[i] = gcn_W[i];   // barrier deferred

  // GAT0 logits + analytic softmax scalars
  float q  = q0v[row];
  float ab = attn_b[0];
  int colg = (lane < cnt) ? mycol : 0;
  float e = -1e30f;
  if(lane < cnt){
    float xx = q + k0v[colg] + ab;
    e = (xx >= 0.f) ? xx : 0.01f * xx;
  }
  float m  = fmaxf(0.f, wmax(e));
  float w  = (lane < cnt) ? expf(e - m) : 0.f;
  float em = expf(-m);
  float Z  = (float)(NTOT - cnt) * em + wsum(w);

  // gather: GCN1 nbr-sum (emb) + GAT0 weighted sum (h0), 4-way unrolled
  float accg = 0.f, acca = 0.f, hs = 0.f;
  int tt = 0;
  for(; tt + 4 <= cnt; tt += 4){
    int c0 = bcasti(mycol, tt),   c1 = bcasti(mycol, tt+1);
    int c2 = bcasti(mycol, tt+2), c3 = bcasti(mycol, tt+3);
    float w0 = bcastf(w, tt),   w1 = bcastf(w, tt+1);
    float w2 = bcastf(w, tt+2), w3 = bcastf(w, tt+3);
    float e0 = all_emb[c0*D + lane], e1 = all_emb[c1*D + lane];
    float e2 = all_emb[c2*D + lane], e3 = all_emb[c3*D + lane];
    float h0v = h0[c0*D + lane], h1v = h0[c1*D + lane];
    float h2v = h0[c2*D + lane], h3v = h0[c3*D + lane];
    accg += (e0 + e1) + (e2 + e3);
    acca = fmaf(w0, h0v, fmaf(w1, h1v, fmaf(w2, h2v, fmaf(w3, h3v, acca))));
    hs   += (h0v + h1v) + (h2v + h3v);
  }
  for(; tt < cnt; ++tt){
    int   c  = bcasti(mycol, tt);
    float wt = bcastf(w, tt);
    float ev = all_emb[c*D + lane];
    float hv = h0[c*D + lane];
    accg += ev;
    acca  = fmaf(wt, hv, acca);
    hs   += hv;
  }
  float g1 = fmaxf((acca + em*(S0[lane] - hs)) / Z, 0.f);

  // gcn1 = relu(accg @ gcnW0 + b0)
  __syncthreads();
  float yg = gcn_b[lane];
  #pragma unroll 16
  for(int k = 0; k < D; ++k) yg = fmaf(bcastf(accg, k), Ws[k*D + lane], yg);
  float gc1 = fmaxf(yg, 0.f);
  gcn1[row*D + lane] = gc1;
  __syncthreads();

  // fuse layer 0
  float l0 = layer_w[0], l1 = layer_w[1];
  float mx = fmaxf(l0, l1);
  float ex0 = expf(l0 - mx), ex1 = expf(l1 - mx);
  float lw0 = ex0 / (ex0 + ex1);
  for(int i = tid; i < D*D; i += 256) Ws[i] = fuse_W[i];
  __syncthreads();
  float y = fuse_b[lane];
  #pragma unroll 16
  for(int k = 0; k < D; ++k) y = fmaf(bcastf(gc1, k), Ws[k*D + lane], y);
  __syncthreads();
  for(int i = tid; i < D*D; i += 256) Ws[i] = fuse_W[D*D + i];
  __syncthreads();
  #pragma unroll 16
  for(int k = 0; k < D; ++k) y = fmaf(bcastf(g1, k), Ws[k*D + lane], y);
  fusedb[row*D + lane] = lw0 * fmaxf(y, 0.f);
  __syncthreads();

  // h1 = g1 @ gatW1 + b1, q1/k1, S1 atomic
  for(int i = tid; i < D*D; i += 256) Ws[i] = gat_W[D*D + i];
  __syncthreads();
  float h = gat_b[D + lane];
  #pragma unroll 16
  for(int k = 0; k < D; ++k) h = fmaf(bcastf(g1, k), Ws[k*D + lane], h);
  h1[row*D + lane] = h;
  float qq = wsum(h * attn_W[2*D + lane]);
  float kk = wsum(h * attn_W[3*D + lane]);
  if(lane == 0){ q1v[row] = qq; k1v[row] = kk; }
  red[wid][lane] = h;
  __syncthreads();
  if(wid == 0)
    atomicAdd(&S1[lane], red[0][lane] + red[1][lane] + red[2][lane] + red[3][lane]);
}

// ---- kC: gcn2 + GAT1 attn + fuse1 ----
__global__ __launch_bounds__(256) void kC(
    const int* __restrict__ ell, const int* __restrict__ nnz,
    const float* __restrict__ gcn1, const float* __restrict__ h1,
    const float* __restrict__ q1v, const float* __restrict__ k1v, const float* __restrict__ S1,
    const float* __restrict__ gcn_W, const float* __restrict__ gcn_b,
    const float* __restrict__ attn_b,
    const float* __restrict__ fuse_W, const float* __restrict__ fuse_b,
    const float* __restrict__ layer_w,
    float* __restrict__ fusedb){
  __shared__ float Ws[D*D];
  int tid = threadIdx.x, lane = tid & 63, wid = tid >> 6;
  int row = blockIdx.x*4 + wid;
  int cnt = nnz[row];
  int mycol = ell[row*MAXN + lane];

  for(int i = tid; i < D*D; i += 256) Ws[i] = gcn_W[D*D + i];

  float q  = q1v[row];
  float ab = attn_b[1];
  int colg = (lane < cnt) ? mycol : 0;
  float e = -1e30f;
  if(lane < cnt){
    float xx = q + k1v[colg] + ab;
    e = (xx >= 0.f) ? xx : 0.01f * xx;
  }
  float m  = fmaxf(0.f, wmax(e));
  float w  = (lane < cnt) ? expf(e - m) : 0.f;
  float em = expf(-m);
  float Z  = (float)(NTOT - cnt) * em + wsum(w);

  float accg = 0.f, acca = 0.f, hs = 0.f;
  int tt = 0;
  for(; tt + 4 <= cnt; tt += 4){
    int c0 = bcasti(mycol, tt),   c1 = bcasti(mycol, tt+1);
    int c2 = bcasti(mycol, tt+2), c3 = bcasti(mycol, tt+3);
    float w0 = bcastf(w, tt),   w1 = bcastf(w, tt+1);
    float w2 = bcastf(w, tt+2), w3 = bcastf(w, tt+3);
    float g0 = gcn1[c0*D + lane], g1_ = gcn1[c1*D + lane];
    float g2_ = gcn1[c2*D + lane], g3 = gcn1[c3*D + lane];
    float h0v = h1[c0*D + lane], h1v = h1[c1*D + lane];
    float h2v = h1[c2*D + lane], h3v = h1[c3*D + lane];
    accg += (g0 + g1_) + (g2_ + g3);
    acca = fmaf(w0, h0v, fmaf(w1, h1v, fmaf(w2, h2v, fmaf(w3, h3v, acca))));
    hs   += (h0v + h1v) + (h2v + h3v);
  }
  for(; tt < cnt; ++tt){
    int   c  = bcasti(mycol, tt);
    float wt = bcastf(w, tt);
    float gv = gcn1[c*D + lane];
    float hv = h1[c*D + lane];
    accg += gv;
    acca  = fmaf(wt, hv, acca);
    hs   += hv;
  }
  float g2 = fmaxf((acca + em*(S1[lane] - hs)) / Z, 0.f);

  __syncthreads();
  float yg = gcn_b[D + lane];
  #pragma unroll 16
  for(int k = 0; k < D; ++k) yg = fmaf(bcastf(accg, k), Ws[k*D + lane], yg);
  float gc2 = fmaxf(yg, 0.f);
  __syncthreads();

  float l0 = layer_w[0], l1 = layer_w[1];
  float mx = fmaxf(l0, l1);
  float ex0 = expf(l0 - mx), ex1 = expf(l1 - mx);
  float lw1 = ex1 / (ex0 + ex1);
  for(int i = tid; i < D*D; i += 256) Ws[i] = fuse_W[2*D*D + i];
  __syncthreads();
  float y = fuse_b[D + lane];
  #pragma unroll 16
  for(int k = 0; k < D; ++k) y = fmaf(bcastf(gc2, k), Ws[k*D + lane], y);
  __syncthreads();
  for(int i = tid; i < D*D; i += 256) Ws[i] = fuse_W[3*D*D + i];
  __syncthreads();
  #pragma unroll 16
  for(int k = 0; k < D; ++k) y = fmaf(bcastf(g2, k), Ws[k*D + lane], y);
  fusedb[row*D + lane] += lw1 * fmaxf(y, 0.f);
}

// ---- kD: scoring + critic ----
__global__ __launch_bounds__(256) void kD(const float* __restrict__ fused,
    const int* __restrict__ users, const int* __restrict__ pos, const int* __restrict__ neg,
    const float* __restrict__ AW, const float* __restrict__ abias,
    const float* __restrict__ cW1, const float* __restrict__ cb1,
    const float* __restrict__ cW2, const float* __restrict__ cb2,
    float* __restrict__ out){
  __shared__ float AWs[D*D];
  __shared__ float C1s[2*D*D];
  __shared__ float abs_[D], cb1s[D], C2s[D];
  int tid = threadIdx.x;
  for(int i = tid; i < D*D; i += 256) AWs[i] = AW[i];
  for(int i = tid; i < 2*D*D; i += 256) C1s[i] = cW1[i];
  if(tid < D){
    abs_[tid] = abias[tid];
    cb1s[tid] = cb1[tid];
    C2s[tid]  = cW2[tid];
  }
  __syncthreads();
  int lane = tid & 63;
  int bi   = blockIdx.x*4 + (tid >> 6);
  int ui = users[bi], pi = pos[bi] + NU, ni = neg[bi] + NU;
  float ud = fused[ui*D + lane], pd = fused[pi*D + lane], nd = fused[ni*D + lane];
  float ufd = abs_[lane];
  #pragma unroll 16
  for(int k = 0; k < D; ++k) ufd = fmaf(bcastf(ud, k), AWs[k*D + lane], ufd);
  float ps = wsum(ufd * pd);
  float ns = wsum(ufd * nd);
  float hu = cb1s[lane];
  #pragma unroll 16
  for(int k = 0; k < D; ++k) hu = fmaf(bcastf(ud, k), C1s[k*D + lane], hu);
  float hp = hu, hn = hu;
  #pragma unroll 16
  for(int k = 0; k < D; ++k){
    float pk = bcastf(pd, k), nk = bcastf(nd, k);
    hp = fmaf(pk, C1s[(D+k)*D + lane], hp);
    hn = fmaf(nk, C1s[(D+k)*D + lane], hn);
  }
  hp = fmaxf(hp, 0.f); hn = fmaxf(hn, 0.f);
  float cp = wsum(hp * C2s[lane]);
  float cn = wsum(hn * C2s[lane]);
  if(lane == 0){
    out[bi]         = ps;
    out[4096  + bi] = ns;
    out[8192  + bi] = cp + cb2[0];
    out[12288 + bi] = cn + cb2[0];
  }
}

extern "C" void kernel_launch(void* const* d_in, const int* in_sizes, int n_in,
                              void* d_out, int out_size, void* d_ws, size_t ws_size,
                              hipStream_t stream){
  const float* adj        = (const float*)d_in[0];
  const int*   users      = (const int*)d_in[1];
  const int*   pos        = (const int*)d_in[2];
  const int*   neg        = (const int*)d_in[3];
  const float* user_table = (const float*)d_in[4];
  const float* item_table = (const float*)d_in[5];
  const float* gcn_W      = (const float*)d_in[6];
  const float* gcn_b      = (const float*)d_in[7];
  const float* gat_W      = (const float*)d_in[8];
  const float* gat_b      = (const float*)d_in[9];
  const float* attn_W     = (const float*)d_in[10];
  const float* attn_b     = (const float*)d_in[11];
  const float* fuse_W     = (const float*)d_in[12];
  const float* fuse_b     = (const float*)d_in[13];
  const float* actor_W    = (const float*)d_in[14];
  const float* actor_b    = (const float*)d_in[15];
  const float* cW1        = (const float*)d_in[16];
  const float* cb1        = (const float*)d_in[17];
  const float* cW2        = (const float*)d_in[18];
  const float* cb2        = (const float*)d_in[19];
  const float* layer_w    = (const float*)d_in[20];

  float* ws      = (float*)d_ws;
  float* all_emb = ws;                   // ND
  float* h0      = all_emb + ND;         // ND
  float* h1      = h0 + ND;              // ND
  float* gcn1    = h1 + ND;              // ND
  float* fusedb  = gcn1 + ND;            // ND
  float* q0v     = fusedb + ND;          // NTOT
  float* k0v     = q0v + NTOT;
  float* q1v     = k0v + NTOT;
  float* k1v     = q1v + NTOT;
  float* S0      = k1v + NTOT;           // D
  float* S1      = S0 + D;               // D
  int*   nnz     = (int*)(S1 + D);       // NTOT
  int*   ell     = nnz + NTOT;           // NTOT*MAXN

  kinit<<<1, 256, 0, stream>>>(S0, S1);
  kA<<<NTOT/4, 256, 0, stream>>>(adj, user_table, item_table, gat_W, gat_b, attn_W,
                                 all_emb, h0, q0v, k0v, S0, ell, nnz);
  kB<<<NTOT/4, 256, 0, stream>>>(all_emb, h0, q0v, k0v, S0, ell, nnz,
                                 gcn_W, gcn_b, gat_W, gat_b, attn_W, attn_b,
                                 fuse_W, fuse_b, layer_w,
                                 gcn1, fusedb, h1, q1v, k1v, S1);
  kC<<<NTOT/4, 256, 0, stream>>>(ell, nnz, gcn1, h1, q1v, k1v, S1,
                                 gcn_W, gcn_b, attn_b, fuse_W, fuse_b, layer_w,
                                 fusedb);
  kD<<<1024, 256, 0, stream>>>(fusedb, users, pos, neg, actor_W, actor_b,
                               cW1, cb1, cW2, cb2, (float*)d_out);
}

// Round 7
// 199.168 us; speedup vs baseline: 1.8497x; 1.0370x over previous
//
#include <hip/hip_runtime.h>

#define NTOT 8192
#define NU 4096
#define D 64
#define MAXN 64
#define ND (NTOT*D)

typedef float f4 __attribute__((ext_vector_type(4)));

__device__ __forceinline__ float wsum(float x){
  #pragma unroll
  for(int o=32;o;o>>=1) x += __shfl_xor(x,o);
  return x;
}
__device__ __forceinline__ float wmax(float x){
  #pragma unroll
  for(int o=32;o;o>>=1) x = fmaxf(x,__shfl_xor(x,o));
  return x;
}
__device__ __forceinline__ float bcastf(float x, int k){
  return __uint_as_float(__builtin_amdgcn_readlane(__float_as_uint(x),(unsigned)k));
}
__device__ __forceinline__ int bcasti(int x, int k){
  return (int)__builtin_amdgcn_readlane((unsigned)x,(unsigned)k);
}

// ---- kA: 2-phase adj scan -> ELL, + concat emb + h0 matmul + q0/k0 + S0 atomic ----
__global__ __launch_bounds__(256) void kA(const float* __restrict__ adj,
    const float* __restrict__ ut, const float* __restrict__ it,
    const float* __restrict__ gat_W, const float* __restrict__ gat_b,
    const float* __restrict__ attn_W,
    float* __restrict__ all_emb, float* __restrict__ h0,
    float* __restrict__ q0v, float* __restrict__ k0v, float* __restrict__ S0,
    int* __restrict__ ell, int* __restrict__ nnz){
  __shared__ float Ws[D*D];
  __shared__ float red[4][D];
  int tid = threadIdx.x, lane = tid & 63, wid = tid >> 6;
  int row = blockIdx.x*4 + wid;
  for(int i = tid; i < D*D; i += 256) Ws[i] = gat_W[i];

  float x = (row < NU) ? ut[row*D + lane] : it[(row-NU)*D + lane];
  all_emb[row*D + lane] = x;

  // -- phase 1: pure streaming scan, nibbles packed into registers --
  const f4* arow = (const f4*)(adj + (size_t)row * NTOT);
  unsigned nibs[4] = {0u,0u,0u,0u};
  #pragma unroll 4
  for(int ch = 0; ch < 32; ++ch){
    f4 v = arow[ch*64 + lane];
    unsigned nib = (v.x!=0.f?1u:0u) | (v.y!=0.f?2u:0u) | (v.z!=0.f?4u:0u) | (v.w!=0.f?8u:0u);
    nibs[ch>>3] |= nib << ((ch&7)*4);
  }

  // -- phase 2: ballot/compact from registers (no memory waits) --
  int base = 0;
  #pragma unroll
  for(int g = 0; g < 4; ++g){
    unsigned ng = nibs[g];
    for(int s = 0; s < 8; ++s){
      unsigned nib = (ng >> (s*4)) & 0xFu;
      if(__ballot(nib != 0u) == 0ull) continue;
      int ch = g*8 + s;
      #pragma unroll
      for(int j = 0; j < 4; ++j){
        unsigned long long m = __ballot(((nib>>j)&1u) != 0u);
        if(m){
          if((nib>>j)&1u){
            int below = __builtin_amdgcn_mbcnt_hi((unsigned)(m>>32),
                        __builtin_amdgcn_mbcnt_lo((unsigned)m, 0u));
            int slot = base + below;
            if(slot < MAXN) ell[row*MAXN + slot] = (ch*64 + lane)*4 + j;
          }
          base += __popcll(m);
        }
      }
    }
  }
  int cnt = base > MAXN ? MAXN : base;
  if(lane == 0) nnz[row] = cnt;

  // h0 = x @ gatW0 + b0
  __syncthreads();
  float h = gat_b[lane];
  #pragma unroll 16
  for(int k = 0; k < D; ++k) h = fmaf(bcastf(x, k), Ws[k*D + lane], h);
  h0[row*D + lane] = h;
  float q  = wsum(h * attn_W[lane]);
  float kk = wsum(h * attn_W[D + lane]);
  if(lane == 0){ q0v[row] = q; k0v[row] = kk; }
  red[wid][lane] = h;
  __syncthreads();
  if(wid == 0)
    atomicAdd(&S0[lane], red[0][lane] + red[1][lane] + red[2][lane] + red[3][lane]);
}

// ---- kB: gcn1 + GAT0 analytic attn + fuse0 + h1/q1/k1 + S1 atomic ----
__global__ __launch_bounds__(256) void kB(
    const float* __restrict__ all_emb, const float* __restrict__ h0,
    const float* __restrict__ q0v, const float* __restrict__ k0v, const float* __restrict__ S0,
    const int* __restrict__ ell, const int* __restrict__ nnz,
    const float* __restrict__ gcn_W, const float* __restrict__ gcn_b,
    const float* __restrict__ gat_W, const float* __restrict__ gat_b,
    const float* __restrict__ attn_W, const float* __restrict__ attn_b,
    const float* __restrict__ fuse_W, const float* __restrict__ fuse_b,
    const float* __restrict__ layer_w,
    float* __restrict__ gcn1, float* __restrict__ fusedb, float* __restrict__ h1,
    float* __restrict__ q1v, float* __restrict__ k1v, float* __restrict__ S1){
  __shared__ float Ws[D*D];
  __shared__ float red[4][D];
  int tid = threadIdx.x, lane = tid & 63, wid = tid >> 6;
  int row = blockIdx.x*4 + wid;
  int cnt = nnz[row];
  int mycol = ell[row*MAXN + lane];

  for(int i = tid; i < D*D; i += 256) Ws[i] = gcn_W[i];   // barrier deferred

  float q  = q0v[row];
  float ab = attn_b[0];
  int colg = (lane < cnt) ? mycol : 0;
  float e = -1e30f;
  if(lane < cnt){
    float xx = q + k0v[colg] + ab;
    e = (xx >= 0.f) ? xx : 0.01f * xx;
  }
  float m  = fmaxf(0.f, wmax(e));
  float w  = (lane < cnt) ? expf(e - m) : 0.f;
  float em = expf(-m);
  float Z  = (float)(NTOT - cnt) * em + wsum(w);

  float accg = 0.f, acca = 0.f, hs = 0.f;
  int tt = 0;
  for(; tt + 4 <= cnt; tt += 4){
    int c0 = bcasti(mycol, tt),   c1 = bcasti(mycol, tt+1);
    int c2 = bcasti(mycol, tt+2), c3 = bcasti(mycol, tt+3);
    float w0 = bcastf(w, tt),   w1 = bcastf(w, tt+1);
    float w2 = bcastf(w, tt+2), w3 = bcastf(w, tt+3);
    float e0 = all_emb[c0*D + lane], e1 = all_emb[c1*D + lane];
    float e2 = all_emb[c2*D + lane], e3 = all_emb[c3*D + lane];
    float h0v = h0[c0*D + lane], h1v = h0[c1*D + lane];
    float h2v = h0[c2*D + lane], h3v = h0[c3*D + lane];
    accg += (e0 + e1) + (e2 + e3);
    acca = fmaf(w0, h0v, fmaf(w1, h1v, fmaf(w2, h2v, fmaf(w3, h3v, acca))));
    hs   += (h0v + h1v) + (h2v + h3v);
  }
  for(; tt < cnt; ++tt){
    int   c  = bcasti(mycol, tt);
    float wt = bcastf(w, tt);
    float ev = all_emb[c*D + lane];
    float hv = h0[c*D + lane];
    accg += ev;
    acca  = fmaf(wt, hv, acca);
    hs   += hv;
  }
  float g1 = fmaxf((acca + em*(S0[lane] - hs)) / Z, 0.f);

  __syncthreads();
  float yg = gcn_b[lane];
  #pragma unroll 16
  for(int k = 0; k < D; ++k) yg = fmaf(bcastf(accg, k), Ws[k*D + lane], yg);
  float gc1 = fmaxf(yg, 0.f);
  gcn1[row*D + lane] = gc1;
  __syncthreads();

  float l0 = layer_w[0], l1 = layer_w[1];
  float mx = fmaxf(l0, l1);
  float ex0 = expf(l0 - mx), ex1 = expf(l1 - mx);
  float lw0 = ex0 / (ex0 + ex1);
  for(int i = tid; i < D*D; i += 256) Ws[i] = fuse_W[i];
  __syncthreads();
  float y = fuse_b[lane];
  #pragma unroll 16
  for(int k = 0; k < D; ++k) y = fmaf(bcastf(gc1, k), Ws[k*D + lane], y);
  __syncthreads();
  for(int i = tid; i < D*D; i += 256) Ws[i] = fuse_W[D*D + i];
  __syncthreads();
  #pragma unroll 16
  for(int k = 0; k < D; ++k) y = fmaf(bcastf(g1, k), Ws[k*D + lane], y);
  fusedb[row*D + lane] = lw0 * fmaxf(y, 0.f);
  __syncthreads();

  for(int i = tid; i < D*D; i += 256) Ws[i] = gat_W[D*D + i];
  __syncthreads();
  float h = gat_b[D + lane];
  #pragma unroll 16
  for(int k = 0; k < D; ++k) h = fmaf(bcastf(g1, k), Ws[k*D + lane], h);
  h1[row*D + lane] = h;
  float qq = wsum(h * attn_W[2*D + lane]);
  float kk = wsum(h * attn_W[3*D + lane]);
  if(lane == 0){ q1v[row] = qq; k1v[row] = kk; }
  red[wid][lane] = h;
  __syncthreads();
  if(wid == 0)
    atomicAdd(&S1[lane], red[0][lane] + red[1][lane] + red[2][lane] + red[3][lane]);
}

// ---- kC: gcn2 + GAT1 attn + fuse1 ----
__global__ __launch_bounds__(256) void kC(
    const int* __restrict__ ell, const int* __restrict__ nnz,
    const float* __restrict__ gcn1, const float* __restrict__ h1,
    const float* __restrict__ q1v, const float* __restrict__ k1v, const float* __restrict__ S1,
    const float* __restrict__ gcn_W, const float* __restrict__ gcn_b,
    const float* __restrict__ attn_b,
    const float* __restrict__ fuse_W, const float* __restrict__ fuse_b,
    const float* __restrict__ layer_w,
    float* __restrict__ fusedb){
  __shared__ float Ws[D*D];
  int tid = threadIdx.x, lane = tid & 63, wid = tid >> 6;
  int row = blockIdx.x*4 + wid;
  int cnt = nnz[row];
  int mycol = ell[row*MAXN + lane];

  for(int i = tid; i < D*D; i += 256) Ws[i] = gcn_W[D*D + i];

  float q  = q1v[row];
  float ab = attn_b[1];
  int colg = (lane < cnt) ? mycol : 0;
  float e = -1e30f;
  if(lane < cnt){
    float xx = q + k1v[colg] + ab;
    e = (xx >= 0.f) ? xx : 0.01f * xx;
  }
  float m  = fmaxf(0.f, wmax(e));
  float w  = (lane < cnt) ? expf(e - m) : 0.f;
  float em = expf(-m);
  float Z  = (float)(NTOT - cnt) * em + wsum(w);

  float accg = 0.f, acca = 0.f, hs = 0.f;
  int tt = 0;
  for(; tt + 4 <= cnt; tt += 4){
    int c0 = bcasti(mycol, tt),   c1 = bcasti(mycol, tt+1);
    int c2 = bcasti(mycol, tt+2), c3 = bcasti(mycol, tt+3);
    float w0 = bcastf(w, tt),   w1 = bcastf(w, tt+1);
    float w2 = bcastf(w, tt+2), w3 = bcastf(w, tt+3);
    float g0 = gcn1[c0*D + lane], g1_ = gcn1[c1*D + lane];
    float g2_ = gcn1[c2*D + lane], g3 = gcn1[c3*D + lane];
    float h0v = h1[c0*D + lane], h1v = h1[c1*D + lane];
    float h2v = h1[c2*D + lane], h3v = h1[c3*D + lane];
    accg += (g0 + g1_) + (g2_ + g3);
    acca = fmaf(w0, h0v, fmaf(w1, h1v, fmaf(w2, h2v, fmaf(w3, h3v, acca))));
    hs   += (h0v + h1v) + (h2v + h3v);
  }
  for(; tt < cnt; ++tt){
    int   c  = bcasti(mycol, tt);
    float wt = bcastf(w, tt);
    float gv = gcn1[c*D + lane];
    float hv = h1[c*D + lane];
    accg += gv;
    acca  = fmaf(wt, hv, acca);
    hs   += hv;
  }
  float g2 = fmaxf((acca + em*(S1[lane] - hs)) / Z, 0.f);

  __syncthreads();
  float yg = gcn_b[D + lane];
  #pragma unroll 16
  for(int k = 0; k < D; ++k) yg = fmaf(bcastf(accg, k), Ws[k*D + lane], yg);
  float gc2 = fmaxf(yg, 0.f);
  __syncthreads();

  float l0 = layer_w[0], l1 = layer_w[1];
  float mx = fmaxf(l0, l1);
  float ex0 = expf(l0 - mx), ex1 = expf(l1 - mx);
  float lw1 = ex1 / (ex0 + ex1);
  for(int i = tid; i < D*D; i += 256) Ws[i] = fuse_W[2*D*D + i];
  __syncthreads();
  float y = fuse_b[D + lane];
  #pragma unroll 16
  for(int k = 0; k < D; ++k) y = fmaf(bcastf(gc2, k), Ws[k*D + lane], y);
  __syncthreads();
  for(int i = tid; i < D*D; i += 256) Ws[i] = fuse_W[3*D*D + i];
  __syncthreads();
  #pragma unroll 16
  for(int k = 0; k < D; ++k) y = fmaf(bcastf(g2, k), Ws[k*D + lane], y);
  fusedb[row*D + lane] += lw1 * fmaxf(y, 0.f);
}

// ---- kD: scoring + critic ----
__global__ __launch_bounds__(256) void kD(const float* __restrict__ fused,
    const int* __restrict__ users, const int* __restrict__ pos, const int* __restrict__ neg,
    const float* __restrict__ AW, const float* __restrict__ abias,
    const float* __restrict__ cW1, const float* __restrict__ cb1,
    const float* __restrict__ cW2, const float* __restrict__ cb2,
    float* __restrict__ out){
  __shared__ float AWs[D*D];
  __shared__ float C1s[2*D*D];
  __shared__ float abs_[D], cb1s[D], C2s[D];
  int tid = threadIdx.x;
  for(int i = tid; i < D*D; i += 256) AWs[i] = AW[i];
  for(int i = tid; i < 2*D*D; i += 256) C1s[i] = cW1[i];
  if(tid < D){
    abs_[tid] = abias[tid];
    cb1s[tid] = cb1[tid];
    C2s[tid]  = cW2[tid];
  }
  __syncthreads();
  int lane = tid & 63;
  int bi   = blockIdx.x*4 + (tid >> 6);
  int ui = users[bi], pi = pos[bi] + NU, ni = neg[bi] + NU;
  float ud = fused[ui*D + lane], pd = fused[pi*D + lane], nd = fused[ni*D + lane];
  float ufd = abs_[lane];
  #pragma unroll 16
  for(int k = 0; k < D; ++k) ufd = fmaf(bcastf(ud, k), AWs[k*D + lane], ufd);
  float ps = wsum(ufd * pd);
  float ns = wsum(ufd * nd);
  float hu = cb1s[lane];
  #pragma unroll 16
  for(int k = 0; k < D; ++k) hu = fmaf(bcastf(ud, k), C1s[k*D + lane], hu);
  float hp = hu, hn = hu;
  #pragma unroll 16
  for(int k = 0; k < D; ++k){
    float pk = bcastf(pd, k), nk = bcastf(nd, k);
    hp = fmaf(pk, C1s[(D+k)*D + lane], hp);
    hn = fmaf(nk, C1s[(D+k)*D + lane], hn);
  }
  hp = fmaxf(hp, 0.f); hn = fmaxf(hn, 0.f);
  float cp = wsum(hp * C2s[lane]);
  float cn = wsum(hn * C2s[lane]);
  if(lane == 0){
    out[bi]         = ps;
    out[4096  + bi] = ns;
    out[8192  + bi] = cp + cb2[0];
    out[12288 + bi] = cn + cb2[0];
  }
}

extern "C" void kernel_launch(void* const* d_in, const int* in_sizes, int n_in,
                              void* d_out, int out_size, void* d_ws, size_t ws_size,
                              hipStream_t stream){
  const float* adj        = (const float*)d_in[0];
  const int*   users      = (const int*)d_in[1];
  const int*   pos        = (const int*)d_in[2];
  const int*   neg        = (const int*)d_in[3];
  const float* user_table = (const float*)d_in[4];
  const float* item_table = (const float*)d_in[5];
  const float* gcn_W      = (const float*)d_in[6];
  const float* gcn_b      = (const float*)d_in[7];
  const float* gat_W      = (const float*)d_in[8];
  const float* gat_b      = (const float*)d_in[9];
  const float* attn_W     = (const float*)d_in[10];
  const float* attn_b     = (const float*)d_in[11];
  const float* fuse_W     = (const float*)d_in[12];
  const float* fuse_b     = (const float*)d_in[13];
  const float* actor_W    = (const float*)d_in[14];
  const float* actor_b    = (const float*)d_in[15];
  const float* cW1        = (const float*)d_in[16];
  const float* cb1        = (const float*)d_in[17];
  const float* cW2        = (const float*)d_in[18];
  const float* cb2        = (const float*)d_in[19];
  const float* layer_w    = (const float*)d_in[20];

  float* ws      = (float*)d_ws;
  float* all_emb = ws;                   // ND
  float* h0      = all_emb + ND;         // ND
  float* h1      = h0 + ND;              // ND
  float* gcn1    = h1 + ND;              // ND
  float* fusedb  = gcn1 + ND;            // ND
  float* q0v     = fusedb + ND;          // NTOT
  float* k0v     = q0v + NTOT;
  float* q1v     = k0v + NTOT;
  float* k1v     = q1v + NTOT;
  float* S0      = k1v + NTOT;           // D
  float* S1      = S0 + D;               // D  (S0,S1 contiguous: one memset)
  int*   nnz     = (int*)(S1 + D);       // NTOT
  int*   ell     = nnz + NTOT;           // NTOT*MAXN

  hipMemsetAsync(S0, 0, 2*D*sizeof(float), stream);
  kA<<<NTOT/4, 256, 0, stream>>>(adj, user_table, item_table, gat_W, gat_b, attn_W,
                                 all_emb, h0, q0v, k0v, S0, ell, nnz);
  kB<<<NTOT/4, 256, 0, stream>>>(all_emb, h0, q0v, k0v, S0, ell, nnz,
                                 gcn_W, gcn_b, gat_W, gat_b, attn_W, attn_b,
                                 fuse_W, fuse_b, layer_w,
                                 gcn1, fusedb, h1, q1v, k1v, S1);
  kC<<<NTOT/4, 256, 0, stream>>>(ell, nnz, gcn1, h1, q1v, k1v, S1,
                                 gcn_W, gcn_b, attn_b, fuse_W, fuse_b, layer_w,
                                 fusedb);
  kD<<<1024, 256, 0, stream>>>(fusedb, users, pos, neg, actor_W, actor_b,
                               cW1, cb1, cW2, cb2, (float*)d_out);
}